// Round 3
// baseline (843.326 us; speedup 1.0000x reference)
//
#include <hip/hip_runtime.h>

#define NPTS 12288
#define DIMS 8
#define EPS2 0.25f
#define MINS 5
#define ROWS 2
#define TI   (256 * ROWS)      // 512 rows per dense block
#define SUBT 256               // j-subtile staged in LDS
#define NJB  16
#define JCHUNK (NPTS / NJB)    // 768
#define NIBD (NPTS / TI)       // 24 (dense kernels)
#define NIB1 (NPTS / 256)      // 48 (per-point kernels)
#define SENT NPTS
#define RMAX 512               // max contracted labels (expected ~100-200)
#define W    (RMAX / 32)       // 16 words per bitmap row
#define BIGL 0x3fffffff

// identical d2 expression everywhere so all passes agree bit-exactly
__device__ __forceinline__ float dist2(const float* xi, const float4& a, const float4& b,
                                       float sqi, float sqj) {
  float dot = 0.f;
  dot = fmaf(xi[0], a.x, dot); dot = fmaf(xi[1], a.y, dot);
  dot = fmaf(xi[2], a.z, dot); dot = fmaf(xi[3], a.w, dot);
  dot = fmaf(xi[4], b.x, dot); dot = fmaf(xi[5], b.y, dot);
  dot = fmaf(xi[6], b.z, dot); dot = fmaf(xi[7], b.w, dot);
  return (sqi + sqj) - 2.0f * dot;
}

// ---------------- kernels ----------------

__global__ __launch_bounds__(256) void k_init(const float* __restrict__ X,
                                              float* __restrict__ sq,
                                              int* __restrict__ density,
                                              int* __restrict__ hook) {
  int i = blockIdx.x * blockDim.x + threadIdx.x;
  if (i >= NPTS) return;
  float s = 0.f;
#pragma unroll
  for (int d = 0; d < DIMS; d++) { float x = X[i * DIMS + d]; s = fmaf(x, x, s); }
  sq[i] = s;
  density[i] = 0;
  hook[i] = i;
}

__global__ __launch_bounds__(256) void k_density(const float* __restrict__ X,
                                                 const float* __restrict__ sq,
                                                 int* __restrict__ density) {
  __shared__ float4 xs[SUBT][2];
  __shared__ float sqs[SUBT];
  int t = threadIdx.x;
  int i0 = blockIdx.x * TI + t, i1 = i0 + 256;
  float xi0[DIMS], xi1[DIMS];
#pragma unroll
  for (int d = 0; d < DIMS; d++) { xi0[d] = X[i0 * DIMS + d]; xi1[d] = X[i1 * DIMS + d]; }
  float sq0 = sq[i0], sq1 = sq[i1];
  int j0 = blockIdx.y * JCHUNK;
  int c0 = 0, c1 = 0;
  for (int js = 0; js < JCHUNK; js += SUBT) {
    __syncthreads();
    {
      int j = j0 + js + t;
      xs[t][0] = ((const float4*)X)[j * 2];
      xs[t][1] = ((const float4*)X)[j * 2 + 1];
      sqs[t] = sq[j];
    }
    __syncthreads();
#pragma unroll 4
    for (int jj = 0; jj < SUBT; jj++) {
      float4 xa = xs[jj][0], xb = xs[jj][1];
      float sj = sqs[jj];
      c0 += (dist2(xi0, xa, xb, sq0, sj) <= EPS2) ? 1 : 0;
      c1 += (dist2(xi1, xa, xb, sq1, sj) <= EPS2) ? 1 : 0;
    }
  }
  atomicAdd(&density[i0], c0);
  atomicAdd(&density[i1], c1);
}

// hook[i] = min(i, min core-neighbor index)
__global__ __launch_bounds__(256) void k_hook(const float* __restrict__ X,
                                              const float* __restrict__ sq,
                                              const int* __restrict__ density,
                                              int* __restrict__ hook) {
  __shared__ float4 xs[SUBT][2];
  __shared__ float sqs[SUBT];
  __shared__ int dns[SUBT];
  int t = threadIdx.x;
  int i0 = blockIdx.x * TI + t, i1 = i0 + 256;
  float xi0[DIMS], xi1[DIMS];
#pragma unroll
  for (int d = 0; d < DIMS; d++) { xi0[d] = X[i0 * DIMS + d]; xi1[d] = X[i1 * DIMS + d]; }
  float sq0 = sq[i0], sq1 = sq[i1];
  int j0 = blockIdx.y * JCHUNK;
  int m0 = SENT, m1 = SENT;
  for (int js = 0; js < JCHUNK; js += SUBT) {
    __syncthreads();
    {
      int j = j0 + js + t;
      xs[t][0] = ((const float4*)X)[j * 2];
      xs[t][1] = ((const float4*)X)[j * 2 + 1];
      sqs[t] = sq[j];
      dns[t] = density[j];
    }
    __syncthreads();
#pragma unroll 4
    for (int jj = 0; jj < SUBT; jj++) {
      float4 xa = xs[jj][0], xb = xs[jj][1];
      float sj = sqs[jj];
      bool corej = (dns[jj] >= MINS);
      int jg = j0 + js + jj;
      if (corej && dist2(xi0, xa, xb, sq0, sj) <= EPS2) m0 = min(m0, jg);
      if (corej && dist2(xi1, xa, xb, sq1, sj) <= EPS2) m1 = min(m1, jg);
    }
  }
  if (m0 < SENT) atomicMin(&hook[i0], m0);
  if (m1 < SENT) atomicMin(&hook[i1], m1);
}

// chase the static hook forest (read-only, strictly decreasing => acyclic)
__global__ __launch_bounds__(256) void k_compress(const int* __restrict__ density,
                                                  const int* __restrict__ hook,
                                                  int* __restrict__ L0) {
  int i = blockIdx.x * blockDim.x + threadIdx.x;
  if (i >= NPTS) return;
  if (density[i] >= MINS) {
    int v = i;
    int h = hook[v];
    while (h != v) { v = h; h = hook[v]; }
    L0[i] = v;
  } else {
    L0[i] = i;
  }
}

// dense ids for forest roots: rid[i] = #roots with index < i ; *Rptr = total
__global__ __launch_bounds__(256) void k_rid(const int* __restrict__ density,
                                             const int* __restrict__ L0,
                                             int* __restrict__ rid,
                                             int* __restrict__ Rptr) {
  __shared__ int wsum[4];
  int t = threadIdx.x;
  int lane = t & 63, wid = t >> 6;
  const int SEG = NPTS / 256;  // 48
  int base = t * SEG;
  int s = 0;
#pragma unroll 4
  for (int k = 0; k < SEG; k++) {
    int i = base + k;
    s += (density[i] >= MINS && L0[i] == i) ? 1 : 0;
  }
  int segsum = s;
#pragma unroll
  for (int off = 1; off < 64; off <<= 1) {
    int n = __shfl_up(s, off, 64);
    if (lane >= off) s += n;
  }
  if (lane == 63) wsum[wid] = s;
  __syncthreads();
  int woff = 0;
  for (int w = 0; w < wid; w++) woff += wsum[w];
  int run = woff + s - segsum;  // exclusive prefix before my segment
#pragma unroll 4
  for (int k = 0; k < SEG; k++) {
    int i = base + k;
    rid[i] = run;
    run += (density[i] >= MINS && L0[i] == i) ? 1 : 0;
  }
  if (t == 255) *Rptr = run;
}

__global__ __launch_bounds__(256) void k_zero(unsigned int* __restrict__ bm,
                                              int* __restrict__ bcount) {
  int idx = blockIdx.x * blockDim.x + threadIdx.x;
  if (idx < RMAX * W) bm[idx] = 0u;
  if (idx == 0) *bcount = 0;
}

// set adjacency bits between contracted labels for crossing core-core edges
__global__ __launch_bounds__(256) void k_fill(const float* __restrict__ X,
                                              const float* __restrict__ sq,
                                              const int* __restrict__ density,
                                              const int* __restrict__ L0,
                                              const int* __restrict__ rid,
                                              unsigned int* __restrict__ bm) {
  __shared__ float4 xs[SUBT][2];
  __shared__ float sqs[SUBT];
  __shared__ int rLs[SUBT];
  int t = threadIdx.x;
  int i0 = blockIdx.x * TI + t, i1 = i0 + 256;
  int a0 = -1, a1 = -1;
  if (density[i0] >= MINS) { int r = rid[L0[i0]]; if (r < RMAX) a0 = r; }
  if (density[i1] >= MINS) { int r = rid[L0[i1]]; if (r < RMAX) a1 = r; }
  float xi0[DIMS], xi1[DIMS];
#pragma unroll
  for (int d = 0; d < DIMS; d++) { xi0[d] = X[i0 * DIMS + d]; xi1[d] = X[i1 * DIMS + d]; }
  float sq0 = sq[i0], sq1 = sq[i1];
  int j0 = blockIdx.y * JCHUNK;
  int s00 = -2, s01 = -2, s02 = -2, s03 = -2;  // seen caches
  int s10 = -2, s11 = -2, s12 = -2, s13 = -2;
  for (int js = 0; js < JCHUNK; js += SUBT) {
    __syncthreads();
    {
      int j = j0 + js + t;
      xs[t][0] = ((const float4*)X)[j * 2];
      xs[t][1] = ((const float4*)X)[j * 2 + 1];
      sqs[t] = sq[j];
      int rl = -1;
      if (density[j] >= MINS) { int r = rid[L0[j]]; if (r < RMAX) rl = r; }
      rLs[t] = rl;
    }
    __syncthreads();
#pragma unroll 4
    for (int jj = 0; jj < SUBT; jj++) {
      float4 xa = xs[jj][0], xb = xs[jj][1];
      float sj = sqs[jj];
      int rl = rLs[jj];
      if (a0 >= 0 && rl >= 0 && rl != a0 && dist2(xi0, xa, xb, sq0, sj) <= EPS2) {
        if (rl != s00 && rl != s01 && rl != s02 && rl != s03) {
          atomicOr(&bm[a0 * W + (rl >> 5)], 1u << (rl & 31));
          atomicOr(&bm[rl * W + (a0 >> 5)], 1u << (a0 & 31));
          s03 = s02; s02 = s01; s01 = s00; s00 = rl;
        }
      }
      if (a1 >= 0 && rl >= 0 && rl != a1 && dist2(xi1, xa, xb, sq1, sj) <= EPS2) {
        if (rl != s10 && rl != s11 && rl != s12 && rl != s13) {
          atomicOr(&bm[a1 * W + (rl >> 5)], 1u << (rl & 31));
          atomicOr(&bm[rl * W + (a1 >> 5)], 1u << (a1 & 31));
          s13 = s12; s12 = s11; s11 = s10; s10 = rl;
        }
      }
    }
  }
}

// connected components of the contracted graph, single block, LDS, internal
// convergence loop (launch sequence stays fixed -> graph-capture safe).
// Output: clab[a] = compact cluster id (rank of component's min root-id).
__global__ __launch_bounds__(RMAX) void k_cc(const unsigned int* __restrict__ bm,
                                             const int* __restrict__ Rptr,
                                             int* __restrict__ clab) {
  __shared__ int lbl[RMAX];
  __shared__ int mn[RMAX];
  __shared__ int chg, cmp;
  int a = threadIdx.x;
  int R = *Rptr; if (R > RMAX) R = RMAX;
  lbl[a] = a;
  __syncthreads();
  while (true) {
    // phase A: min neighbor label
    int m = lbl[a];
    if (a < R) {
      const unsigned int* row = bm + a * W;
#pragma unroll
      for (int w = 0; w < W; w++) {
        unsigned int bits = row[w];
        while (bits) {
          int b = __ffs(bits) - 1;
          bits &= bits - 1;
          m = min(m, lbl[(w << 5) + b]);
        }
      }
    }
    mn[a] = m;
    if (a == 0) chg = 0;
    __syncthreads();
    // phase B: hook
    int l = lbl[a];
    if (m < l) { atomicMin(&lbl[l], m); atomicMin(&lbl[a], m); chg = 1; }
    __syncthreads();
    // phase C: full compression to fixpoint
    while (true) {
      if (a == 0) cmp = 0;
      __syncthreads();
      int nl = lbl[lbl[a]];
      __syncthreads();
      if (nl < lbl[a]) { lbl[a] = nl; cmp = 1; }
      __syncthreads();
      if (!cmp) break;
    }
    if (!chg) break;
    __syncthreads();
  }
  // ranks: cluster id = exclusive prefix of "is component root" at the root
  int flag = (a < R && lbl[a] == a) ? 1 : 0;
  mn[a] = flag;
  __syncthreads();
  for (int off = 1; off < RMAX; off <<= 1) {
    int v = mn[a];
    int add = (a >= off) ? mn[a - off] : 0;
    __syncthreads();
    mn[a] = v + add;
    __syncthreads();
  }
  clab[a] = mn[lbl[a]] - 1;  // inclusive at root includes its own flag
}

// per-point labels; collect border (non-core) points into a compact list
__global__ __launch_bounds__(256) void k_labels(const int* __restrict__ density,
                                                const int* __restrict__ rid,
                                                const int* __restrict__ clab,
                                                int* __restrict__ labArr,  // aliases L0 (in: root, out: label)
                                                int* __restrict__ blist,
                                                int* __restrict__ bcount,
                                                float* __restrict__ out) {
  int i = blockIdx.x * blockDim.x + threadIdx.x;
  if (i >= NPTS) return;
  if (density[i] >= MINS) {
    int r = rid[labArr[i]];
    if (r >= RMAX) r = RMAX - 1;
    int lab = clab[r];
    labArr[i] = lab;
    out[i] = (float)lab;
  } else {
    labArr[i] = BIGL;
    out[i] = -1.0f;
    int pos = atomicAdd(bcount, 1);
    blist[pos] = i;
  }
}

// one block per border point: min cluster id over core neighbors
__global__ __launch_bounds__(256) void k_border(const float* __restrict__ X,
                                                const float* __restrict__ sq,
                                                const int* __restrict__ labArr,
                                                const int* __restrict__ blist,
                                                const int* __restrict__ bcount,
                                                float* __restrict__ out) {
  __shared__ int wm[4];
  int t = threadIdx.x;
  int lane = t & 63, wid = t >> 6;
  int count = *bcount;
  for (int k = blockIdx.x; k < count; k += gridDim.x) {
    int p = blist[k];
    float xp[DIMS];
#pragma unroll
    for (int d = 0; d < DIMS; d++) xp[d] = X[p * DIMS + d];
    float sqp = sq[p];
    int m = BIGL;
    for (int j = t; j < NPTS; j += 256) {
      float4 xa = ((const float4*)X)[j * 2];
      float4 xb = ((const float4*)X)[j * 2 + 1];
      float d2 = dist2(xp, xa, xb, sqp, sq[j]);
      if (d2 <= EPS2) m = min(m, labArr[j]);   // BIGL for non-cores
    }
#pragma unroll
    for (int off = 32; off >= 1; off >>= 1) m = min(m, __shfl_xor(m, off, 64));
    if (lane == 0) wm[wid] = m;
    __syncthreads();
    if (t == 0) {
      int mm = min(min(wm[0], wm[1]), min(wm[2], wm[3]));
      out[p] = (mm < BIGL) ? (float)mm : -1.0f;
    }
    __syncthreads();
  }
}

// ---------------- launch ----------------

extern "C" void kernel_launch(void* const* d_in, const int* in_sizes, int n_in,
                              void* d_out, int out_size, void* d_ws, size_t ws_size,
                              hipStream_t stream) {
  const float* X = (const float*)d_in[0];
  float* out = (float*)d_out;

  char* ws = (char*)d_ws;
  float* sq      = (float*)(ws);                       // 48 KB
  int*   density = (int*)(ws + 4 * NPTS);              // 48 KB
  int*   hook    = (int*)(ws + 8 * NPTS);              // 48 KB (-> rid after compress)
  int*   L0      = (int*)(ws + 12 * NPTS);             // 48 KB (-> labArr after labels)
  int*   blist   = (int*)(ws + 16 * NPTS);             // 48 KB
  unsigned int* bitmap = (unsigned int*)(ws + 20 * NPTS);        // 32 KB
  int*   clab    = (int*)(ws + 20 * NPTS + 4 * RMAX * W);        // 2 KB
  int*   Rptr    = (int*)(ws + 20 * NPTS + 4 * RMAX * W + 4 * RMAX);
  int*   bcount  = Rptr + 1;
  int*   rid     = hook;   // hook dead after k_compress

  dim3 gridD(NIBD, NJB);

  k_init<<<NIB1, 256, 0, stream>>>(X, sq, density, hook);
  k_density<<<gridD, 256, 0, stream>>>(X, sq, density);
  k_hook<<<gridD, 256, 0, stream>>>(X, sq, density, hook);
  k_compress<<<NIB1, 256, 0, stream>>>(density, hook, L0);
  k_rid<<<1, 256, 0, stream>>>(density, L0, rid, Rptr);
  k_zero<<<(RMAX * W + 255) / 256, 256, 0, stream>>>(bitmap, bcount);
  k_fill<<<gridD, 256, 0, stream>>>(X, sq, density, L0, rid, bitmap);
  k_cc<<<1, RMAX, 0, stream>>>(bitmap, Rptr, clab);
  k_labels<<<NIB1, 256, 0, stream>>>(density, rid, clab, L0, blist, bcount, out);
  k_border<<<256, 256, 0, stream>>>(X, sq, L0, blist, bcount, out);
}

// Round 4
// 393.435 us; speedup vs baseline: 2.1435x; 2.1435x over previous
//
#include <hip/hip_runtime.h>

#define NPTS 12288
#define DIMS 8
#define EPS2 0.25f
#define MINS 5
#define ROWS 2
#define TI   (256 * ROWS)      // 512 rows per dense block
#define SUBT 256               // j-subtile staged in LDS
#define NJB  24
#define JCHUNK (NPTS / NJB)    // 512 (2 subtiles)
#define NIBD (NPTS / TI)       // 24 (dense kernels)
#define NIB1 (NPTS / 256)      // 48 (per-point kernels)
#define SENT NPTS
#define RMAX 512               // max contracted labels (R~120 measured OK in R3)
#define W    (RMAX / 32)       // 16 words per bitmap row
#define BIGL 0x3fffffff

// identical d2 expression everywhere so all passes agree bit-exactly
__device__ __forceinline__ float dist2(const float* xi, const float4& a, const float4& b,
                                       float sqi, float sqj) {
  float dot = 0.f;
  dot = fmaf(xi[0], a.x, dot); dot = fmaf(xi[1], a.y, dot);
  dot = fmaf(xi[2], a.z, dot); dot = fmaf(xi[3], a.w, dot);
  dot = fmaf(xi[4], b.x, dot); dot = fmaf(xi[5], b.y, dot);
  dot = fmaf(xi[6], b.z, dot); dot = fmaf(xi[7], b.w, dot);
  return (sqi + sqj) - 2.0f * dot;
}

// ---------------- kernels ----------------

__global__ __launch_bounds__(256) void k_init(const float* __restrict__ X,
                                              float* __restrict__ sq,
                                              int* __restrict__ density,
                                              int* __restrict__ hook) {
  int i = blockIdx.x * blockDim.x + threadIdx.x;
  if (i >= NPTS) return;
  float s = 0.f;
#pragma unroll
  for (int d = 0; d < DIMS; d++) { float x = X[i * DIMS + d]; s = fmaf(x, x, s); }
  sq[i] = s;
  density[i] = 0;
  hook[i] = i;
}

__global__ __launch_bounds__(256) void k_density(const float* __restrict__ X,
                                                 const float* __restrict__ sq,
                                                 int* __restrict__ density) {
  __shared__ float4 xs[SUBT][2];
  __shared__ float sqs[SUBT];
  int t = threadIdx.x;
  int i0 = blockIdx.x * TI + t, i1 = i0 + 256;
  float xi0[DIMS], xi1[DIMS];
#pragma unroll
  for (int d = 0; d < DIMS; d++) { xi0[d] = X[i0 * DIMS + d]; xi1[d] = X[i1 * DIMS + d]; }
  float sq0 = sq[i0], sq1 = sq[i1];
  int j0 = blockIdx.y * JCHUNK;
  int c0 = 0, c1 = 0;
  for (int js = 0; js < JCHUNK; js += SUBT) {
    __syncthreads();
    {
      int j = j0 + js + t;
      xs[t][0] = ((const float4*)X)[j * 2];
      xs[t][1] = ((const float4*)X)[j * 2 + 1];
      sqs[t] = sq[j];
    }
    __syncthreads();
#pragma unroll 4
    for (int jj = 0; jj < SUBT; jj++) {
      float4 xa = xs[jj][0], xb = xs[jj][1];
      float sj = sqs[jj];
      c0 += (dist2(xi0, xa, xb, sq0, sj) <= EPS2) ? 1 : 0;
      c1 += (dist2(xi1, xa, xb, sq1, sj) <= EPS2) ? 1 : 0;
    }
  }
  atomicAdd(&density[i0], c0);
  atomicAdd(&density[i1], c1);
}

// hook[i] = min(i, min core-neighbor index)
__global__ __launch_bounds__(256) void k_hook(const float* __restrict__ X,
                                              const float* __restrict__ sq,
                                              const int* __restrict__ density,
                                              int* __restrict__ hook) {
  __shared__ float4 xs[SUBT][2];
  __shared__ float sqs[SUBT];
  __shared__ int dns[SUBT];
  int t = threadIdx.x;
  int i0 = blockIdx.x * TI + t, i1 = i0 + 256;
  float xi0[DIMS], xi1[DIMS];
#pragma unroll
  for (int d = 0; d < DIMS; d++) { xi0[d] = X[i0 * DIMS + d]; xi1[d] = X[i1 * DIMS + d]; }
  float sq0 = sq[i0], sq1 = sq[i1];
  int j0 = blockIdx.y * JCHUNK;
  int m0 = SENT, m1 = SENT;
  for (int js = 0; js < JCHUNK; js += SUBT) {
    __syncthreads();
    {
      int j = j0 + js + t;
      xs[t][0] = ((const float4*)X)[j * 2];
      xs[t][1] = ((const float4*)X)[j * 2 + 1];
      sqs[t] = sq[j];
      dns[t] = density[j];
    }
    __syncthreads();
#pragma unroll 4
    for (int jj = 0; jj < SUBT; jj++) {
      float4 xa = xs[jj][0], xb = xs[jj][1];
      float sj = sqs[jj];
      bool corej = (dns[jj] >= MINS);
      int jg = j0 + js + jj;
      if (corej && dist2(xi0, xa, xb, sq0, sj) <= EPS2) m0 = min(m0, jg);
      if (corej && dist2(xi1, xa, xb, sq1, sj) <= EPS2) m1 = min(m1, jg);
    }
  }
  if (m0 < SENT) atomicMin(&hook[i0], m0);
  if (m1 < SENT) atomicMin(&hook[i1], m1);
}

// chase the static hook forest (read-only, strictly decreasing => acyclic)
__global__ __launch_bounds__(256) void k_compress(const int* __restrict__ density,
                                                  const int* __restrict__ hook,
                                                  int* __restrict__ L0) {
  int i = blockIdx.x * blockDim.x + threadIdx.x;
  if (i >= NPTS) return;
  if (density[i] >= MINS) {
    int v = i;
    int h = hook[v];
    while (h != v) { v = h; h = hook[v]; }
    L0[i] = v;
  } else {
    L0[i] = i;
  }
}

// dense ids for forest roots: rid[i] = #roots with index < i ; *Rptr = total
__global__ __launch_bounds__(256) void k_rid(const int* __restrict__ density,
                                             const int* __restrict__ L0,
                                             int* __restrict__ rid,
                                             int* __restrict__ Rptr) {
  __shared__ int wsum[4];
  int t = threadIdx.x;
  int lane = t & 63, wid = t >> 6;
  const int SEG = NPTS / 256;  // 48
  int base = t * SEG;
  int s = 0;
#pragma unroll 4
  for (int k = 0; k < SEG; k++) {
    int i = base + k;
    s += (density[i] >= MINS && L0[i] == i) ? 1 : 0;
  }
  int segsum = s;
#pragma unroll
  for (int off = 1; off < 64; off <<= 1) {
    int n = __shfl_up(s, off, 64);
    if (lane >= off) s += n;
  }
  if (lane == 63) wsum[wid] = s;
  __syncthreads();
  int woff = 0;
  for (int w = 0; w < wid; w++) woff += wsum[w];
  int run = woff + s - segsum;  // exclusive prefix before my segment
#pragma unroll 4
  for (int k = 0; k < SEG; k++) {
    int i = base + k;
    rid[i] = run;
    run += (density[i] >= MINS && L0[i] == i) ? 1 : 0;
  }
  if (t == 255) *Rptr = run;
}

__global__ __launch_bounds__(256) void k_zero(unsigned int* __restrict__ bm,
                                              int* __restrict__ bcount) {
  int idx = blockIdx.x * blockDim.x + threadIdx.x;
  if (idx < RMAX * W) bm[idx] = 0u;
  if (idx == 0) *bcount = 0;
}

// set adjacency bits between contracted labels for crossing core-core edges.
// ALL hot-loop atomics are LDS; one batched nonzero-word merge to global at end.
__global__ __launch_bounds__(256) void k_fill(const float* __restrict__ X,
                                              const float* __restrict__ sq,
                                              const int* __restrict__ density,
                                              const int* __restrict__ L0,
                                              const int* __restrict__ rid,
                                              unsigned int* __restrict__ bm) {
  __shared__ unsigned int bmLds[RMAX * W];   // 32 KB private bitmap
  __shared__ float4 xs[SUBT][2];
  __shared__ float sqs[SUBT];
  __shared__ int rLs[SUBT];
  int t = threadIdx.x;
#pragma unroll
  for (int w = 0; w < RMAX * W / 256; w++) bmLds[t + w * 256] = 0u;
  int i0 = blockIdx.x * TI + t, i1 = i0 + 256;
  int a0 = -1, a1 = -1;
  if (density[i0] >= MINS) { int r = rid[L0[i0]]; if (r < RMAX) a0 = r; }
  if (density[i1] >= MINS) { int r = rid[L0[i1]]; if (r < RMAX) a1 = r; }
  float xi0[DIMS], xi1[DIMS];
#pragma unroll
  for (int d = 0; d < DIMS; d++) { xi0[d] = X[i0 * DIMS + d]; xi1[d] = X[i1 * DIMS + d]; }
  float sq0 = sq[i0], sq1 = sq[i1];
  int j0 = blockIdx.y * JCHUNK;
  for (int js = 0; js < JCHUNK; js += SUBT) {
    __syncthreads();   // also covers the bmLds zero-init on first iteration
    {
      int j = j0 + js + t;
      xs[t][0] = ((const float4*)X)[j * 2];
      xs[t][1] = ((const float4*)X)[j * 2 + 1];
      sqs[t] = sq[j];
      int rl = -1;
      if (density[j] >= MINS) { int r = rid[L0[j]]; if (r < RMAX) rl = r; }
      rLs[t] = rl;
    }
    __syncthreads();
#pragma unroll 4
    for (int jj = 0; jj < SUBT; jj++) {
      float4 xa = xs[jj][0], xb = xs[jj][1];
      float sj = sqs[jj];
      int rl = rLs[jj];
      if (a0 >= 0 && rl >= 0 && rl != a0 && dist2(xi0, xa, xb, sq0, sj) <= EPS2) {
        atomicOr(&bmLds[a0 * W + (rl >> 5)], 1u << (rl & 31));
        atomicOr(&bmLds[rl * W + (a0 >> 5)], 1u << (a0 & 31));
      }
      if (a1 >= 0 && rl >= 0 && rl != a1 && dist2(xi1, xa, xb, sq1, sj) <= EPS2) {
        atomicOr(&bmLds[a1 * W + (rl >> 5)], 1u << (rl & 31));
        atomicOr(&bmLds[rl * W + (a1 >> 5)], 1u << (a1 & 31));
      }
    }
  }
  __syncthreads();
  // batched merge: only nonzero words, no-return global OR
#pragma unroll
  for (int w = 0; w < RMAX * W / 256; w++) {
    int idx = t + w * 256;
    unsigned int v = bmLds[idx];
    if (v) atomicOr(&bm[idx], v);
  }
}

// connected components of the contracted graph, single block, LDS, internal
// convergence loop (launch sequence stays fixed -> graph-capture safe).
__global__ __launch_bounds__(RMAX) void k_cc(const unsigned int* __restrict__ bm,
                                             const int* __restrict__ Rptr,
                                             int* __restrict__ clab) {
  __shared__ int lbl[RMAX];
  __shared__ int mn[RMAX];
  __shared__ int chg, cmp;
  int a = threadIdx.x;
  int R = *Rptr; if (R > RMAX) R = RMAX;
  lbl[a] = a;
  __syncthreads();
  while (true) {
    // phase A: min neighbor label
    int m = lbl[a];
    if (a < R) {
      const unsigned int* row = bm + a * W;
#pragma unroll
      for (int w = 0; w < W; w++) {
        unsigned int bits = row[w];
        while (bits) {
          int b = __ffs(bits) - 1;
          bits &= bits - 1;
          m = min(m, lbl[(w << 5) + b]);
        }
      }
    }
    mn[a] = m;
    if (a == 0) chg = 0;
    __syncthreads();
    // phase B: hook
    int l = lbl[a];
    if (m < l) { atomicMin(&lbl[l], m); atomicMin(&lbl[a], m); chg = 1; }
    __syncthreads();
    // phase C: full compression to fixpoint
    while (true) {
      if (a == 0) cmp = 0;
      __syncthreads();
      int nl = lbl[lbl[a]];
      __syncthreads();
      if (nl < lbl[a]) { lbl[a] = nl; cmp = 1; }
      __syncthreads();
      if (!cmp) break;
    }
    if (!chg) break;
    __syncthreads();
  }
  // cluster id = rank of component root (roots ascend in contracted-id order,
  // which ascends in min-core-index order -> matches reference ordering)
  int flag = (a < R && lbl[a] == a) ? 1 : 0;
  mn[a] = flag;
  __syncthreads();
  for (int off = 1; off < RMAX; off <<= 1) {
    int v = mn[a];
    int add = (a >= off) ? mn[a - off] : 0;
    __syncthreads();
    mn[a] = v + add;
    __syncthreads();
  }
  clab[a] = mn[lbl[a]] - 1;  // inclusive at root includes its own flag
}

// per-point labels; collect border (non-core) points into a compact list
__global__ __launch_bounds__(256) void k_labels(const int* __restrict__ density,
                                                const int* __restrict__ rid,
                                                const int* __restrict__ clab,
                                                int* __restrict__ labArr,  // aliases L0
                                                int* __restrict__ blist,
                                                int* __restrict__ bcount,
                                                float* __restrict__ out) {
  int i = blockIdx.x * blockDim.x + threadIdx.x;
  if (i >= NPTS) return;
  if (density[i] >= MINS) {
    int r = rid[labArr[i]];
    if (r >= RMAX) r = RMAX - 1;
    int lab = clab[r];
    labArr[i] = lab;
    out[i] = (float)lab;
  } else {
    labArr[i] = BIGL;
    out[i] = -1.0f;
    int pos = atomicAdd(bcount, 1);
    blist[pos] = i;
  }
}

// one block per border point: min cluster id over core neighbors
__global__ __launch_bounds__(256) void k_border(const float* __restrict__ X,
                                                const float* __restrict__ sq,
                                                const int* __restrict__ labArr,
                                                const int* __restrict__ blist,
                                                const int* __restrict__ bcount,
                                                float* __restrict__ out) {
  __shared__ int wm[4];
  int t = threadIdx.x;
  int lane = t & 63, wid = t >> 6;
  int count = *bcount;
  for (int k = blockIdx.x; k < count; k += gridDim.x) {
    int p = blist[k];
    float xp[DIMS];
#pragma unroll
    for (int d = 0; d < DIMS; d++) xp[d] = X[p * DIMS + d];
    float sqp = sq[p];
    int m = BIGL;
    for (int j = t; j < NPTS; j += 256) {
      float4 xa = ((const float4*)X)[j * 2];
      float4 xb = ((const float4*)X)[j * 2 + 1];
      float d2 = dist2(xp, xa, xb, sqp, sq[j]);
      if (d2 <= EPS2) m = min(m, labArr[j]);   // BIGL for non-cores
    }
#pragma unroll
    for (int off = 32; off >= 1; off >>= 1) m = min(m, __shfl_xor(m, off, 64));
    if (lane == 0) wm[wid] = m;
    __syncthreads();
    if (t == 0) {
      int mm = min(min(wm[0], wm[1]), min(wm[2], wm[3]));
      out[p] = (mm < BIGL) ? (float)mm : -1.0f;
    }
    __syncthreads();
  }
}

// ---------------- launch ----------------

extern "C" void kernel_launch(void* const* d_in, const int* in_sizes, int n_in,
                              void* d_out, int out_size, void* d_ws, size_t ws_size,
                              hipStream_t stream) {
  const float* X = (const float*)d_in[0];
  float* out = (float*)d_out;

  char* ws = (char*)d_ws;
  float* sq      = (float*)(ws);                       // 48 KB
  int*   density = (int*)(ws + 4 * NPTS);              // 48 KB
  int*   hook    = (int*)(ws + 8 * NPTS);              // 48 KB (-> rid after compress)
  int*   L0      = (int*)(ws + 12 * NPTS);             // 48 KB (-> labArr after labels)
  int*   blist   = (int*)(ws + 16 * NPTS);             // 48 KB
  unsigned int* bitmap = (unsigned int*)(ws + 20 * NPTS);        // 32 KB
  int*   clab    = (int*)(ws + 20 * NPTS + 4 * RMAX * W);        // 2 KB
  int*   Rptr    = (int*)(ws + 20 * NPTS + 4 * RMAX * W + 4 * RMAX);
  int*   bcount  = Rptr + 1;
  int*   rid     = hook;   // hook dead after k_compress

  dim3 gridD(NIBD, NJB);

  k_init<<<NIB1, 256, 0, stream>>>(X, sq, density, hook);
  k_density<<<gridD, 256, 0, stream>>>(X, sq, density);
  k_hook<<<gridD, 256, 0, stream>>>(X, sq, density, hook);
  k_compress<<<NIB1, 256, 0, stream>>>(density, hook, L0);
  k_rid<<<1, 256, 0, stream>>>(density, L0, rid, Rptr);
  k_zero<<<(RMAX * W + 255) / 256, 256, 0, stream>>>(bitmap, bcount);
  k_fill<<<gridD, 256, 0, stream>>>(X, sq, density, L0, rid, bitmap);
  k_cc<<<1, RMAX, 0, stream>>>(bitmap, Rptr, clab);
  k_labels<<<NIB1, 256, 0, stream>>>(density, rid, clab, L0, blist, bcount, out);
  k_border<<<256, 256, 0, stream>>>(X, sq, L0, blist, bcount, out);
}